// Round 4
// baseline (113.496 us; speedup 1.0000x reference)
//
#include <hip/hip_runtime.h>

// GroupNorm+Swish backward, fused. Round 4 = Round 3 + compile fix
// (__builtin_nontemporal_store needs ext_vector_type, not HIP float4 class).
// N=32, C=64, G=32, CG=2, HXW=16384.
// out = [dx (N*C*HXW) | dgamma (C*HXW) | dbeta (C*HXW)], all f32.
//
// R2 post-mortem: float2 got 2048 blocks but occupancy stalled at 54%,
// VALUBusy 9%, effective 4.1 TB/s -> still latency-bound. R3/R4: split the
// n-reduction over grid.z=2 (16 n's per thread) so we keep 2048 blocks
// (32 waves/CU) AND float4 (1KB/wave/instr). dgamma/dbeta combined via
// atomicAdd with exactly 2 contributions per address onto a zeroed buffer:
// float add is commutative, so 2-way atomic accumulation is deterministic.

#define N_TOT 32
#define C_TOT 64
#define G_TOT 32
#define HXW_TOT 16384
#define HXW4 (HXW_TOT / 4)
#define NSPLIT 2
#define NPER (N_TOT / NSPLIT)

typedef float f4 __attribute__((ext_vector_type(4)));

__global__ __launch_bounds__(256) void gnswish_bwd(
    const float* __restrict__ dy,
    const float* __restrict__ mean,
    const float* __restrict__ rstd,
    const float* __restrict__ x,
    const float* __restrict__ gamma,
    const float* __restrict__ beta,
    float* __restrict__ out)
{
    const int hw4 = blockIdx.x * blockDim.x + threadIdx.x;  // 0..4095
    const int c   = blockIdx.y;                             // 0..63
    const int z   = blockIdx.z;                             // 0..1
    const int g   = c >> 1;                                 // CG = 2

    const float gam = gamma[c];
    const float bet = beta[c];

    const f4* __restrict__ dy4 = (const f4*)dy;
    const f4* __restrict__ x4  = (const f4*)x;
    f4* __restrict__ dx4       = (f4*)out;

    float dg0 = 0.f, dg1 = 0.f, dg2 = 0.f, dg3 = 0.f;
    float db0 = 0.f, db1 = 0.f, db2 = 0.f, db3 = 0.f;

    const int n0 = z * NPER;
#pragma unroll 4
    for (int k = 0; k < NPER; ++k) {
        const int n = n0 + k;
        const float mu = mean[n * G_TOT + g];   // block-uniform -> s_load
        const float rs = rstd[n * G_TOT + g];
        const long  idx = (long)(n * C_TOT + c) * HXW4 + hw4;

        const f4 d  = dy4[idx];
        const f4 xv = x4[idx];

        f4 dxv;

#define DO_COMP(XX, DD, DGG, DBB, DXX)                                   \
        {                                                                \
            float xn  = (XX - mu) * rs;                                  \
            float o   = xn * gam + bet;                                  \
            float sig = __builtin_amdgcn_rcpf(1.0f + __expf(-o));        \
            float sw  = o * sig;                                         \
            float sg  = sig + sw * (1.0f - sig);                         \
            float ds  = DD * sg;                                         \
            DGG += ds * xn;                                              \
            DBB += ds;                                                   \
            DXX = ds * (gam * rs);                                       \
        }

        DO_COMP(xv.x, d.x, dg0, db0, dxv.x)
        DO_COMP(xv.y, d.y, dg1, db1, dxv.y)
        DO_COMP(xv.z, d.z, dg2, db2, dxv.z)
        DO_COMP(xv.w, d.w, dg3, db3, dxv.w)
#undef DO_COMP

        __builtin_nontemporal_store(dxv, &dx4[idx]);
    }

    // dgamma at float offset N*C*HXW, dbeta at + C*HXW. 2 atomic contributions
    // per address (z=0, z=1) onto zeroed memory -> deterministic (commutative).
    const long dgf  = (long)N_TOT * C_TOT * HXW_TOT;
    const long dbf  = dgf + (long)C_TOT * HXW_TOT;
    const long colf = (long)c * HXW_TOT + (long)hw4 * 4;

    atomicAdd(&out[dgf + colf + 0], dg0);
    atomicAdd(&out[dgf + colf + 1], dg1);
    atomicAdd(&out[dgf + colf + 2], dg2);
    atomicAdd(&out[dgf + colf + 3], dg3);
    atomicAdd(&out[dbf + colf + 0], db0);
    atomicAdd(&out[dbf + colf + 1], db1);
    atomicAdd(&out[dbf + colf + 2], db2);
    atomicAdd(&out[dbf + colf + 3], db3);
}

extern "C" void kernel_launch(void* const* d_in, const int* in_sizes, int n_in,
                              void* d_out, int out_size, void* d_ws, size_t ws_size,
                              hipStream_t stream) {
    const float* dy    = (const float*)d_in[0];
    const float* mean  = (const float*)d_in[1];
    const float* rstd  = (const float*)d_in[2];
    const float* x     = (const float*)d_in[3];
    const float* gamma = (const float*)d_in[4];
    const float* beta  = (const float*)d_in[5];
    float* out = (float*)d_out;

    // Zero the dgamma/dbeta region (8 MB) so 2-way atomic accumulate is exact.
    const size_t dg_off_f = (size_t)N_TOT * C_TOT * HXW_TOT;
    (void)hipMemsetAsync(out + dg_off_f, 0,
                         (size_t)2 * C_TOT * HXW_TOT * sizeof(float), stream);

    dim3 grid(HXW4 / 256, C_TOT, NSPLIT);  // 16 x 64 x 2 = 2048 blocks
    dim3 block(256);
    gnswish_bwd<<<grid, block, 0, stream>>>(dy, mean, rstd, x, gamma, beta, out);
}

// Round 5
// 65.653 us; speedup vs baseline: 1.7287x; 1.7287x over previous
//
#include <hip/hip_runtime.h>

// GroupNorm+Swish backward, fused single kernel. Round 5: revert to R2
// structure (best, 67.0 us) + unroll 8.
// N=32, C=64, G=32, CG=2, HXW=16384.
// dy:(N,G,CG,HXW)  mean:(N,G)  rstd:(N,G)  x:(N,C,H,W)  gamma:(C)  beta:(C)
// out = [dx (N*C*HXW) | dgamma (C*HXW) | dbeta (C*HXW)]
// dy, x, dx all share flat layout [N][C][HXW].
//
// Roofline accounting: logical bytes = 268 MB read + 142 MB write = 410 MB,
// each byte touched exactly once. R2 = 410 MB / 67 us = 6.12 TB/s = 97% of
// the 6.29 TB/s copy ceiling. R4 (atomic n-split, 60% occ) regressed ->
// occupancy is not the constraint; this is the fabric/HBM wall.

#define N_TOT 32
#define C_TOT 64
#define G_TOT 32
#define HXW_TOT 16384
#define HXW2 (HXW_TOT / 2)

typedef float f2 __attribute__((ext_vector_type(2)));

__global__ __launch_bounds__(256) void gnswish_bwd(
    const float* __restrict__ dy,
    const float* __restrict__ mean,
    const float* __restrict__ rstd,
    const float* __restrict__ x,
    const float* __restrict__ gamma,
    const float* __restrict__ beta,
    float* __restrict__ out)
{
    const int hw2 = blockIdx.x * blockDim.x + threadIdx.x;  // 0..8191 (float2 idx)
    const int c   = blockIdx.y;                             // 0..63
    const int g   = c >> 1;                                 // CG = 2

    const float gam = gamma[c];
    const float bet = beta[c];

    const f2* __restrict__ dy2 = (const f2*)dy;
    const f2* __restrict__ x2  = (const f2*)x;
    f2* __restrict__ dx2       = (f2*)out;

    float dg0 = 0.f, dg1 = 0.f;
    float db0 = 0.f, db1 = 0.f;

#pragma unroll 8
    for (int n = 0; n < N_TOT; ++n) {
        const float mu = mean[n * G_TOT + g];   // block-uniform -> s_load
        const float rs = rstd[n * G_TOT + g];
        const long  idx = (long)(n * C_TOT + c) * HXW2 + hw2;

        const f2 d  = dy2[idx];
        const f2 xv = x2[idx];

        f2 dxv;

#define DO_COMP(XX, DD, DGG, DBB, DXX)                                   \
        {                                                                \
            float xn  = (XX - mu) * rs;                                  \
            float o   = xn * gam + bet;                                  \
            float sig = __builtin_amdgcn_rcpf(1.0f + __expf(-o));        \
            float sw  = o * sig;                                         \
            float sg  = sig + sw * (1.0f - sig);                         \
            float ds  = DD * sg;                                         \
            DGG += ds * xn;                                              \
            DBB += ds;                                                   \
            DXX = ds * (gam * rs);                                       \
        }

        DO_COMP(xv.x, d.x, dg0, db0, dxv.x)
        DO_COMP(xv.y, d.y, dg1, db1, dxv.y)
#undef DO_COMP

        __builtin_nontemporal_store(dxv, &dx2[idx]);
    }

    // dgamma at float offset N*C*HXW, dbeta at N*C*HXW + C*HXW (in f2 units)
    const long dg_base = (long)N_TOT * C_TOT * HXW2;
    const long db_base = dg_base + (long)C_TOT * HXW2;
    const long col     = (long)c * HXW2 + hw2;

    f2* __restrict__ o2 = (f2*)out;
    f2 dgv; dgv.x = dg0; dgv.y = dg1;
    f2 dbv; dbv.x = db0; dbv.y = db1;
    __builtin_nontemporal_store(dgv, &o2[dg_base + col]);
    __builtin_nontemporal_store(dbv, &o2[db_base + col]);
}

extern "C" void kernel_launch(void* const* d_in, const int* in_sizes, int n_in,
                              void* d_out, int out_size, void* d_ws, size_t ws_size,
                              hipStream_t stream) {
    const float* dy    = (const float*)d_in[0];
    const float* mean  = (const float*)d_in[1];
    const float* rstd  = (const float*)d_in[2];
    const float* x     = (const float*)d_in[3];
    const float* gamma = (const float*)d_in[4];
    const float* beta  = (const float*)d_in[5];
    float* out = (float*)d_out;

    dim3 grid(HXW2 / 256, C_TOT);  // 32 x 64 = 2048 blocks -> 8 wg/CU
    dim3 block(256);
    gnswish_bwd<<<grid, block, 0, stream>>>(dy, mean, rstd, x, gamma, beta, out);
}